// Round 7
// baseline (511.827 us; speedup 1.0000x reference)
//
#include <hip/hip_runtime.h>
#include <math.h>

typedef __bf16 bf16;
typedef __bf16 bf16x8 __attribute__((ext_vector_type(8)));
typedef __bf16 bf16x4v __attribute__((ext_vector_type(4)));
typedef float f32x4 __attribute__((ext_vector_type(4)));

#define NB 4
#define NT 2048
#define NC 2048
#define NH 16
#define ND 128
#define NROW (NB*NT)   // 8192

#define GLD16(g, l) __builtin_amdgcn_global_load_lds( \
    (__attribute__((address_space(1))) void*)(g), \
    (__attribute__((address_space(3))) void*)(l), 16, 0, 0)

// ---------------- fused: x fp32 -> bf16  AND  omega = sigmoid((x.w_omega+b)/16) ----------------
__global__ void cvtx_omega_kernel(const float* __restrict__ x, bf16* __restrict__ xb,
                                  const float* __restrict__ w_om, const float* __restrict__ b_om,
                                  float* __restrict__ omega) {
  int row = blockIdx.x;
  const float4* xr = reinterpret_cast<const float4*>(x + (size_t)row * NC);
  const float4* wr = reinterpret_cast<const float4*>(w_om);
  bf16x4v* ob = reinterpret_cast<bf16x4v*>(xb + (size_t)row * NC);
  float sum = 0.f;
  for (int i = threadIdx.x; i < NC/4; i += 256) {
    float4 a = xr[i], b = wr[i];
    sum += a.x*b.x + a.y*b.y + a.z*b.z + a.w*b.w;
    bf16x4v o;
    o[0] = (bf16)a.x; o[1] = (bf16)a.y; o[2] = (bf16)a.z; o[3] = (bf16)a.w;
    ob[i] = o;
  }
  for (int m = 32; m; m >>= 1) sum += __shfl_xor(sum, m);
  __shared__ float wsum[4];
  if ((threadIdx.x & 63) == 0) wsum[threadIdx.x >> 6] = sum;
  __syncthreads();
  if (threadIdx.x == 0) {
    float d = wsum[0] + wsum[1] + wsum[2] + wsum[3] + b_om[0];
    omega[row] = 1.f / (1.f + expf(-d * (1.f/16.f)));
  }
}

// ---------------- fp32 -> bf16 convert: all 4 weight matrices in one launch ----------------
__global__ void cvtw_kernel(const float* __restrict__ W0, const float* __restrict__ W1,
                            const float* __restrict__ W2, const float* __restrict__ W3,
                            bf16* __restrict__ o0, bf16* __restrict__ o1,
                            bf16* __restrict__ o2, bf16* __restrict__ o3) {
  int which = blockIdx.x >> 12;   // 4096 blocks per weight
  const float* in = which == 0 ? W0 : which == 1 ? W1 : which == 2 ? W2 : W3;
  bf16* out = which == 0 ? o0 : which == 1 ? o1 : which == 2 ? o2 : o3;
  int i = (blockIdx.x & 4095) * 256 + threadIdx.x;   // < NC*NC/4
  float4 v = reinterpret_cast<const float4*>(in)[i];
  bf16x4v o;
  o[0] = (bf16)v.x; o[1] = (bf16)v.y; o[2] = (bf16)v.z; o[3] = (bf16)v.w;
  reinterpret_cast<bf16x4v*>(out)[i] = o;
}

// ---------------- exclusive cumsum over T per batch (fp64 accumulation) ----------------
__global__ void scan_kernel(const float* __restrict__ omega, float* __restrict__ phi) {
  int b = blockIdx.x;
  const float* om = omega + (size_t)b * NT;
  float* ph = phi + (size_t)b * NT;
  int t = threadIdx.x;
  float v[8]; float s = 0.f;
  #pragma unroll
  for (int j = 0; j < 8; j++) { v[j] = om[t*8 + j]; s += v[j]; }
  __shared__ float totals[256];
  __shared__ double base_sh[256];
  totals[t] = s;
  __syncthreads();
  if (t == 0) {
    double run = 0.0;
    for (int i = 0; i < 256; i++) { base_sh[i] = run; run += (double)totals[i]; }
  }
  __syncthreads();
  double run = base_sh[t];
  #pragma unroll
  for (int j = 0; j < 8; j++) { ph[t*8 + j] = (float)run; run += (double)v[j]; }
}

// ---------------- cos/sin table: [row][dd], dd in 0..63 ----------------
__global__ void sincos_kernel(const float* __restrict__ phi, const float* __restrict__ log_freq,
                              float* __restrict__ cos_t, float* __restrict__ sin_t) {
  int i = blockIdx.x * 256 + threadIdx.x;   // < NROW*64
  int row = i >> 6, dd = i & 63;
  float f = expf(log_freq[dd]);
  float a = phi[row] * f;
  float si, co;
  sincosf(a, &si, &co);
  cos_t[i] = co;
  sin_t[i] = si;
}

// ---------------- 256x256 GEMM, counted-vmcnt pipeline ----------------
// 512 threads = 8 waves (4M x 2N), BK=64, LDS 128KB dbuf.
// Staging split into 4 phase-aligned groups (s1=A-M0, s2=B-N0, s3=A-M1, s4=B-N1),
// one group staged per phase for tile t+1; vmcnt(4) keeps 4-6 loads in flight always
// (never drains to 0 in the main loop). LDS rows remapped so groups are contiguous:
//   A: lds_row = (mi>>1)*128 + wm*32 + (mi&1)*16 + l15   (M0 half in rows 0-127)
//   B: lds_row = (nj>>2)*128 + wn*64 + (nj&3)*16 + l15   (N0 half in rows 0-127)
// MODE 0: rotate+rmsnorm epilogue (x outscale), bf16 | MODE 1: bf16 transposed Vt | MODE 2: fp32
template<int MODE>
__global__ __launch_bounds__(512, 2)
void gemm256(const bf16* __restrict__ Ag, const bf16* __restrict__ Bg,
             void* __restrict__ Cout,
             const float* __restrict__ cos_t, const float* __restrict__ sin_t,
             const float* __restrict__ gamma, float outscale) {
  constexpr int NKT = NC / 64;   // 32 K-tiles
  __shared__ bf16 Als[2][256 * 64];
  __shared__ bf16 Bls[2][256 * 64];
  const int t = threadIdx.x;
  const int lane = t & 63, lg = lane >> 4, l15 = lane & 15;
  const int wid = t >> 6, wm = wid >> 1, wn = wid & 1;
  const int bid = blockIdx.x;
  const int wg = (bid & 7) * 32 + (bid >> 3);
  const int m0 = (wg >> 3) * 256, n0 = (wg & 7) * 256;

  const size_t K2 = (size_t)NC * 2;
  const int tr = t >> 3;
  const int scol = ((t & 7) * 16) ^ ((tr & 7) << 4);
  // grouped-stage source rows: group g covers LDS rows g*64+tr
  const int mA_g0 = ((tr >> 5) * 64) + (tr & 31);            // L=tr
  const int mA_g1 = (((64 + tr) >> 5) * 64) + ((64 + tr) & 31);
  const char* a1s0 = (const char*)Ag + (size_t)(m0 + mA_g0) * K2 + scol;
  const char* a1s1 = (const char*)Ag + (size_t)(m0 + mA_g1) * K2 + scol;
  const char* a3s0 = (const char*)Ag + (size_t)(m0 + mA_g0 + 32) * K2 + scol;
  const char* a3s1 = (const char*)Ag + (size_t)(m0 + mA_g1 + 32) * K2 + scol;
  const char* b2s0 = (const char*)Bg + (size_t)(n0 + tr) * K2 + scol;
  const char* b2s1 = (const char*)Bg + (size_t)(n0 + 128 + tr) * K2 + scol;
  const char* b4s0 = (const char*)Bg + (size_t)(n0 + 64 + tr) * K2 + scol;
  const char* b4s1 = (const char*)Bg + (size_t)(n0 + 192 + tr) * K2 + scol;

  const int colk0 = (lg * 16) ^ ((l15 & 7) << 4);
  const int colk1 = colk0 ^ 64;
  int arowL[4], browL[8];
  #pragma unroll
  for (int mi = 0; mi < 4; mi++)
    arowL[mi] = (((mi >> 1) * 128) + wm * 32 + ((mi & 1) * 16) + l15) * 128;
  #pragma unroll
  for (int nj = 0; nj < 8; nj++)
    browL[nj] = (((nj >> 2) * 128) + wn * 64 + ((nj & 3) * 16) + l15) * 128;

  f32x4 acc[4][8] = {};

#define STAGE_S1(kt, dd) do { char* _d = (char*)&Als[dd][0] + t * 16; \
    GLD16(a1s0 + (size_t)(kt) * 128, _d); GLD16(a1s1 + (size_t)(kt) * 128, _d + 8192); } while(0)
#define STAGE_S2(kt, dd) do { char* _d = (char*)&Bls[dd][0] + t * 16; \
    GLD16(b2s0 + (size_t)(kt) * 128, _d); GLD16(b2s1 + (size_t)(kt) * 128, _d + 8192); } while(0)
#define STAGE_S3(kt, dd) do { char* _d = (char*)&Als[dd][0] + 16384 + t * 16; \
    GLD16(a3s0 + (size_t)(kt) * 128, _d); GLD16(a3s1 + (size_t)(kt) * 128, _d + 8192); } while(0)
#define STAGE_S4(kt, dd) do { char* _d = (char*)&Bls[dd][0] + 16384 + t * 16; \
    GLD16(b4s0 + (size_t)(kt) * 128, _d); GLD16(b4s1 + (size_t)(kt) * 128, _d + 8192); } while(0)

#define MFMA16(IB, JB) do { \
    _Pragma("unroll") \
    for (int kk = 0; kk < 2; kk++) \
      _Pragma("unroll") \
      for (int i = 0; i < 2; i++) \
        _Pragma("unroll") \
        for (int j = 0; j < 4; j++) \
          acc[(IB)+i][(JB)+j] = __builtin_amdgcn_mfma_f32_16x16x32_bf16(aC[i][kk], bC[j][kk], acc[(IB)+i][(JB)+j], 0,0,0); \
  } while(0)

#define RD_A(mibase) do { \
    _Pragma("unroll") \
    for (int i = 0; i < 2; i++) { \
      aC[i][0] = *(const bf16x8*)(Ab + arowL[(mibase)+i] + colk0); \
      aC[i][1] = *(const bf16x8*)(Ab + arowL[(mibase)+i] + colk1); } \
  } while(0)
#define RD_B(njbase) do { \
    _Pragma("unroll") \
    for (int j = 0; j < 4; j++) { \
      bC[j][0] = *(const bf16x8*)(Bb + browL[(njbase)+j] + colk0); \
      bC[j][1] = *(const bf16x8*)(Bb + browL[(njbase)+j] + colk1); } \
  } while(0)

  // prologue: stage tile 0, drain s1,s2 only (s3,s4 stay in flight)
  STAGE_S1(0, 0); STAGE_S2(0, 0); STAGE_S3(0, 0); STAGE_S4(0, 0);
  asm volatile("s_waitcnt vmcnt(4)" ::: "memory");
  __builtin_amdgcn_s_barrier();
  asm volatile("" ::: "memory");

  bf16x8 aC[2][2], bC[4][2];
  for (int kt = 0; kt < NKT - 1; kt++) {
    const int d = kt & 1;
    const char* Ab = (const char*)&Als[d][0];
    const char* Bb = (const char*)&Bls[d][0];

    // ph1: A-M0 + B-N0 -> MFMA M0N0 ; stage s1(t+1) ; drain s3
    RD_A(0); RD_B(0);
    STAGE_S1(kt + 1, d ^ 1);
    asm volatile("s_waitcnt vmcnt(4)" ::: "memory");
    __builtin_amdgcn_s_barrier();
    asm volatile("s_waitcnt lgkmcnt(0)" ::: "memory");
    __builtin_amdgcn_s_setprio(1);
    MFMA16(0, 0);
    __builtin_amdgcn_s_setprio(0);
    __builtin_amdgcn_s_barrier();

    // ph2: A-M1 -> MFMA M1N0 ; stage s2(t+1) ; drain s4
    RD_A(2);
    STAGE_S2(kt + 1, d ^ 1);
    asm volatile("s_waitcnt vmcnt(4)" ::: "memory");
    __builtin_amdgcn_s_barrier();
    asm volatile("s_waitcnt lgkmcnt(0)" ::: "memory");
    __builtin_amdgcn_s_setprio(1);
    MFMA16(2, 0);
    __builtin_amdgcn_s_setprio(0);
    __builtin_amdgcn_s_barrier();

    // ph3: B-N1 -> MFMA M1N1 ; stage s3(t+1) ; no wait needed
    RD_B(4);
    STAGE_S3(kt + 1, d ^ 1);
    __builtin_amdgcn_s_barrier();
    asm volatile("s_waitcnt lgkmcnt(0)" ::: "memory");
    __builtin_amdgcn_s_setprio(1);
    MFMA16(2, 4);
    __builtin_amdgcn_s_setprio(0);
    __builtin_amdgcn_s_barrier();

    // ph4: A-M0 again -> MFMA M0N1 ; stage s4(t+1) ; drain s1',s2' for next ph1
    RD_A(0);
    STAGE_S4(kt + 1, d ^ 1);
    asm volatile("s_waitcnt vmcnt(4)" ::: "memory");
    __builtin_amdgcn_s_barrier();
    asm volatile("s_waitcnt lgkmcnt(0)" ::: "memory");
    __builtin_amdgcn_s_setprio(1);
    MFMA16(0, 4);
    __builtin_amdgcn_s_setprio(0);
    __builtin_amdgcn_s_barrier();
  }

  // tail tile (no stages); drain everything at its first barrier
  {
    const int d = (NKT - 1) & 1;
    const char* Ab = (const char*)&Als[d][0];
    const char* Bb = (const char*)&Bls[d][0];
    RD_A(0); RD_B(0);
    asm volatile("s_waitcnt vmcnt(0)" ::: "memory");
    __builtin_amdgcn_s_barrier();
    asm volatile("s_waitcnt lgkmcnt(0)" ::: "memory");
    MFMA16(0, 0);
    __builtin_amdgcn_s_barrier();
    RD_A(2);
    __builtin_amdgcn_s_barrier();
    asm volatile("s_waitcnt lgkmcnt(0)" ::: "memory");
    MFMA16(2, 0);
    __builtin_amdgcn_s_barrier();
    RD_B(4);
    __builtin_amdgcn_s_barrier();
    asm volatile("s_waitcnt lgkmcnt(0)" ::: "memory");
    MFMA16(2, 4);
    __builtin_amdgcn_s_barrier();
    RD_A(0);
    __builtin_amdgcn_s_barrier();
    asm volatile("s_waitcnt lgkmcnt(0)" ::: "memory");
    MFMA16(0, 4);
  }
#undef STAGE_S1
#undef STAGE_S2
#undef STAGE_S3
#undef STAGE_S4
#undef MFMA16
#undef RD_A
#undef RD_B

  if constexpr (MODE == 0) {
    bf16* out = (bf16*)Cout;
    #pragma unroll
    for (int mi = 0; mi < 4; mi++) {
      #pragma unroll
      for (int r = 0; r < 4; r++) {
        int m = m0 + wm*64 + mi*16 + lg*4 + r;
        float ss = 0.f;
        #pragma unroll
        for (int nj = 0; nj < 8; nj++) { float v = acc[mi][nj][r]; ss += v*v; }
        ss += __shfl_xor(ss, 1); ss += __shfl_xor(ss, 2);
        ss += __shfl_xor(ss, 4); ss += __shfl_xor(ss, 8);
        float scale = rsqrtf(ss * (1.f/128.f) + 1e-5f) * outscale;
        size_t rowb = (size_t)m * NC + n0 + wn*128;
        size_t tabb = (size_t)m * 64;
        #pragma unroll
        for (int nj = 0; nj < 4; nj++) {
          int dd = nj*16 + l15;
          float c = cos_t[tabb + dd];
          float s = sin_t[tabb + dd];
          float t1 = acc[mi][nj][r], t2 = acc[mi][nj+4][r];
          float o1 = (t1*c + t2*s) * scale * gamma[dd];
          float o2 = (t2*c - t1*s) * scale * gamma[dd + 64];
          out[rowb + dd] = (bf16)o1;
          out[rowb + dd + 64] = (bf16)o2;
        }
      }
    }
  } else if constexpr (MODE == 1) {
    bf16* vt = (bf16*)Cout;
    const int h = (n0 + wn*128) >> 7;
    #pragma unroll
    for (int mi = 0; mi < 4; mi++) {
      #pragma unroll
      for (int r = 0; r < 4; r++) {
        int m = m0 + wm*64 + mi*16 + lg*4 + r;
        int bidx = m >> 11, tt = m & (NT-1);
        size_t hb = (((size_t)bidx * NH + h) * ND) * NT + tt;
        #pragma unroll
        for (int nj = 0; nj < 8; nj++) {
          int d = nj*16 + l15;
          vt[hb + (size_t)d * NT] = (bf16)acc[mi][nj][r];
        }
      }
    }
  } else {
    float* out = (float*)Cout;
    #pragma unroll
    for (int mi = 0; mi < 4; mi++) {
      #pragma unroll
      for (int r = 0; r < 4; r++) {
        int m = m0 + wm*64 + mi*16 + lg*4 + r;
        size_t rowb = (size_t)m * NC + n0 + wn*128;
        #pragma unroll
        for (int nj = 0; nj < 8; nj++)
          out[rowb + nj*16 + l15] = acc[mi][nj][r];
      }
    }
  }
}

// ---------------- causal flash attention v4b (unchanged from round 6) ----------------
__global__ __launch_bounds__(512, 2)
void fa_kernel(const bf16* __restrict__ Qg, const bf16* __restrict__ Kg,
               const bf16* __restrict__ Vt, bf16* __restrict__ Og) {
  __shared__ bf16 Kls[2][64 * 128];   // 32 KB
  __shared__ bf16 Vls[128 * 64];      // 16 KB
  __shared__ bf16 Pls[8][32 * 64];    // 32 KB, XOR-swizzled rows
  const int t = threadIdx.x, w = t >> 6, lane = t & 63, lg = lane >> 4, l15 = lane & 15;
  const int bh = blockIdx.x;
  const int qb = (gridDim.y - 1) - blockIdx.y;
  const size_t qkbase = (size_t)(bh >> 4) * NT * NC + (size_t)(bh & 15) * ND;
  const size_t vbase  = (size_t)bh * ND * NT;
  const int q0 = qb * 256 + w * 32;

  bf16x8 qf[2][4];
  #pragma unroll
  for (int mt = 0; mt < 2; mt++)
    #pragma unroll
    for (int kc = 0; kc < 4; kc++)
      qf[mt][kc] = *reinterpret_cast<const bf16x8*>(
          Qg + qkbase + (size_t)(q0 + mt*16 + l15) * NC + kc*32 + lg*8);

  f32x4 oacc[2][8] = {};
  f32x4 lacc[2] = {};
  float m_run[2][4];
  #pragma unroll
  for (int mt = 0; mt < 2; mt++)
    #pragma unroll
    for (int r = 0; r < 4; r++) m_run[mt][r] = -1e30f;

  bf16x8 vone;
  #pragma unroll
  for (int i = 0; i < 8; i++) vone[i] = (bf16)1.0f;

  const int kinS = ((t & 15) * 16) ^ (((t >> 4) & 7) << 4);
  const char* ksrc0 = (const char*)(Kg + qkbase) + (size_t)(t >> 4) * (NC*2) + kinS;
  const int vinS = ((t & 7) * 16) ^ (((t >> 3) & 7) << 4);
  const char* vsrc0 = (const char*)(Vt + vbase) + (size_t)(t >> 3) * (NT*2) + vinS;

#define STAGE_K(kt, dd) do { \
    const char* ks_ = ksrc0 + (size_t)(kt) * 64 * (NC*2); \
    char* kd_ = (char*)&Kls[dd][0] + t * 16; \
    GLD16(ks_,                        kd_); \
    GLD16(ks_ + (size_t)32 * NC * 2,  kd_ + 8192); \
  } while(0)
#define STAGE_V(kt) do { \
    const char* vs_ = vsrc0 + (size_t)(kt) * 128; \
    char* vd_ = (char*)&Vls[0] + t * 16; \
    GLD16(vs_,                        vd_); \
    GLD16(vs_ + (size_t)64 * NT * 2,  vd_ + 8192); \
  } while(0)

  const int ntiles = 4 * qb + 4;
  STAGE_K(0, 0);
  __syncthreads();

  for (int kt = 0; kt < ntiles; kt++) {
    const int d = kt & 1;
    const int kv0 = kt * 64;
    if (kt + 1 < ntiles) STAGE_K(kt + 1, d ^ 1);
    STAGE_V(kt);

    const bool active = (q0 + 31 >= kv0);
    if (active) {
      f32x4 s[2][4] = {};
      __builtin_amdgcn_s_setprio(1);
      #pragma unroll
      for (int kc = 0; kc < 4; kc++) {
        bf16x8 kf[4];
        const int swz = ((kc*64 + lg*16) ^ ((l15 & 7) << 4));
        #pragma unroll
        for (int nt = 0; nt < 4; nt++)
          kf[nt] = *reinterpret_cast<const bf16x8*>((const char*)&Kls[d][0] + (nt*16 + l15) * 256 + swz);
        #pragma unroll
        for (int mt = 0; mt < 2; mt++)
          #pragma unroll
          for (int nt = 0; nt < 4; nt++)
            s[mt][nt] = __builtin_amdgcn_mfma_f32_16x16x32_bf16(qf[mt][kc], kf[nt], s[mt][nt], 0, 0, 0);
      }
      __builtin_amdgcn_s_setprio(0);

      if (kv0 + 63 > q0) {
        #pragma unroll
        for (int mt = 0; mt < 2; mt++)
          #pragma unroll
          for (int nt = 0; nt < 4; nt++) {
            int kv = kv0 + nt*16 + l15;
            #pragma unroll
            for (int r = 0; r < 4; r++)
              if (kv > q0 + mt*16 + lg*4 + r) s[mt][nt][r] = -1e30f;
          }
      }

      float tmax[2][4];
      #pragma unroll
      for (int mt = 0; mt < 2; mt++)
        #pragma unroll
        for (int r = 0; r < 4; r++) {
          float tm = fmaxf(fmaxf(s[mt][0][r], s[mt][1][r]), fmaxf(s[mt][2][r], s[mt][3][r]));
          tm = fmaxf(tm, __shfl_xor(tm, 1));
          tm = fmaxf(tm, __shfl_xor(tm, 2));
          tm = fmaxf(tm, __shfl_xor(tm, 4));
          tm = fmaxf(tm, __shfl_xor(tm, 8));
          tmax[mt][r] = tm;
        }

      int ok = 1;
      #pragma unroll
      for (int mt = 0; mt < 2; mt++)
        #pragma unroll
        for (int r = 0; r < 4; r++) ok &= (tmax[mt][r] <= m_run[mt][r] + 8.0f);
      if (!__all(ok)) {
        #pragma unroll
        for (int mt = 0; mt < 2; mt++) {
          f32x4 alv;
          #pragma unroll
          for (int r = 0; r < 4; r++) {
            float mn = fmaxf(m_run[mt][r], tmax[mt][r]);
            alv[r] = exp2f(m_run[mt][r] - mn);
            m_run[mt][r] = mn;
          }
          #pragma unroll
          for (int dt = 0; dt < 8; dt++) {
            f32x4 o = oacc[mt][dt];
            o[0] *= alv[0]; o[1] *= alv[1]; o[2] *= alv[2]; o[3] *= alv[3];
            oacc[mt][dt] = o;
          }
          f32x4 lv = lacc[mt];
          lv[0] *= alv[0]; lv[1] *= alv[1]; lv[2] *= alv[2]; lv[3] *= alv[3];
          lacc[mt] = lv;
        }
      }

      char* pw = (char*)&Pls[w][0];
      #pragma unroll
      for (int mt = 0; mt < 2; mt++)
        #pragma unroll
        for (int r = 0; r < 4; r++) {
          float p0 = exp2f(s[mt][0][r] - m_run[mt][r]);
          float p1 = exp2f(s[mt][1][r] - m_run[mt][r]);
          float p2 = exp2f(s[mt][2][r] - m_run[mt][r]);
          float p3 = exp2f(s[mt][3][r] - m_run[mt][r]);
          int qrow = mt*16 + lg*4 + r;
          int rb = qrow * 128, cX = (qrow & 7) << 4;
          *(bf16*)(pw + rb + ((       2*l15) ^ cX)) = (bf16)p0;
          *(bf16*)(pw + rb + (( 32 +  2*l15) ^ cX)) = (bf16)p1;
          *(bf16*)(pw + rb + (( 64 +  2*l15) ^ cX)) = (bf16)p2;
          *(bf16*)(pw + rb + (( 96 +  2*l15) ^ cX)) = (bf16)p3;
        }
    }

    asm volatile("s_waitcnt vmcnt(0)" ::: "memory");
    __builtin_amdgcn_s_barrier();
    asm volatile("" ::: "memory");

    if (active) {
      char* pw = (char*)&Pls[w][0];
      bf16x8 pf[2][2];
      #pragma unroll
      for (int mt = 0; mt < 2; mt++)
        #pragma unroll
        for (int kc2 = 0; kc2 < 2; kc2++)
          pf[mt][kc2] = *reinterpret_cast<const bf16x8*>(
              pw + (mt*16 + l15) * 128 + ((kc2*64 + lg*16) ^ ((l15 & 7) << 4)));
      __builtin_amdgcn_s_setprio(1);
      #pragma unroll
      for (int kc2 = 0; kc2 < 2; kc2++) {
        #pragma unroll
        for (int mt = 0; mt < 2; mt++)
          lacc[mt] = __builtin_amdgcn_mfma_f32_16x16x32_bf16(pf[mt][kc2], vone, lacc[mt], 0, 0, 0);
        const int swz = ((kc2*64 + lg*16) ^ ((l15 & 7) << 4));
        #pragma unroll
        for (int dt = 0; dt < 8; dt++) {
          bf16x8 vf = *reinterpret_cast<const bf16x8*>((const char*)&Vls[0] + (dt*16 + l15) * 128 + swz);
          #pragma unroll
          for (int mt = 0; mt < 2; mt++)
            oacc[mt][dt] = __builtin_amdgcn_mfma_f32_16x16x32_bf16(pf[mt][kc2], vf, oacc[mt][dt], 0, 0, 0);
        }
      }
      __builtin_amdgcn_s_setprio(0);
    }

    __syncthreads();
  }
#undef STAGE_K
#undef STAGE_V

  #pragma unroll
  for (int mt = 0; mt < 2; mt++)
    #pragma unroll
    for (int r = 0; r < 4; r++) {
      float inv = 1.f / lacc[mt][r];
      size_t orow = qkbase + (size_t)(q0 + mt*16 + lg*4 + r) * NC;
      #pragma unroll
      for (int dt = 0; dt < 8; dt++)
        Og[orow + dt*16 + l15] = (bf16)(oacc[mt][dt][r] * inv);
    }
}

// ---------------- host launch ----------------
extern "C" void kernel_launch(void* const* d_in, const int* in_sizes, int n_in,
                              void* d_out, int out_size, void* d_ws, size_t ws_size,
                              hipStream_t stream) {
  (void)in_sizes; (void)n_in; (void)out_size; (void)ws_size;
  const float* x       = (const float*)d_in[0];
  const float* Wq      = (const float*)d_in[1];
  const float* Wk      = (const float*)d_in[2];
  const float* Wv      = (const float*)d_in[3];
  const float* Wo      = (const float*)d_in[4];
  const float* w_omega = (const float*)d_in[5];
  const float* b_omega = (const float*)d_in[6];
  const float* log_freq= (const float*)d_in[7];
  const float* q_gamma = (const float*)d_in[8];
  const float* k_gamma = (const float*)d_in[9];

  char* p = (char*)d_ws;
  auto alloc = [&](size_t bytes) { void* r = (void*)p; p += (bytes + 255) & ~(size_t)255; return r; };
  bf16* xb   = (bf16*)alloc((size_t)NROW * NC * 2);
  bf16* wqb  = (bf16*)alloc((size_t)NC * NC * 2);
  bf16* wkb  = (bf16*)alloc((size_t)NC * NC * 2);
  bf16* wvb  = (bf16*)alloc((size_t)NC * NC * 2);
  bf16* wob  = (bf16*)alloc((size_t)NC * NC * 2);
  bf16* qb   = (bf16*)alloc((size_t)NROW * NC * 2);
  bf16* kb   = (bf16*)alloc((size_t)NROW * NC * 2);
  bf16* vt   = (bf16*)alloc((size_t)NROW * NC * 2);  // transposed V: [B][H][D][T]
  bf16* ob   = (bf16*)alloc((size_t)NROW * NC * 2);
  float* omega = (float*)alloc((size_t)NROW * 4);
  float* phi   = (float*)alloc((size_t)NROW * 4);
  float* cos_t = (float*)alloc((size_t)NROW * 64 * 4);
  float* sin_t = (float*)alloc((size_t)NROW * 64 * 4);

  cvtx_omega_kernel<<<NROW, 256, 0, stream>>>(x, xb, w_omega, b_omega, omega);
  cvtw_kernel<<<16384, 256, 0, stream>>>(Wq, Wk, Wv, Wo, wqb, wkb, wvb, wob);
  scan_kernel<<<NB, 256, 0, stream>>>(omega, phi);
  sincos_kernel<<<NROW * 64 / 256, 256, 0, stream>>>(phi, log_freq, cos_t, sin_t);

  const float sc2 = 0.12751726f;   // log2(e)/sqrt(128), folded into q
  gemm256<0><<<256, 512, 0, stream>>>(xb, wqb, qb, cos_t, sin_t, q_gamma, sc2);
  gemm256<0><<<256, 512, 0, stream>>>(xb, wkb, kb, cos_t, sin_t, k_gamma, 1.0f);
  gemm256<1><<<256, 512, 0, stream>>>(xb, wvb, vt, nullptr, nullptr, nullptr, 1.0f);

  fa_kernel<<<dim3(NB * NH, NT / 256), 512, 0, stream>>>(qb, kb, vt, ob);

  gemm256<2><<<256, 512, 0, stream>>>(ob, wob, d_out, nullptr, nullptr, nullptr, 1.0f);
}

// Round 8
// 462.791 us; speedup vs baseline: 1.1060x; 1.1060x over previous
//
#include <hip/hip_runtime.h>
#include <math.h>

typedef __bf16 bf16;
typedef __bf16 bf16x8 __attribute__((ext_vector_type(8)));
typedef __bf16 bf16x4v __attribute__((ext_vector_type(4)));
typedef float f32x4 __attribute__((ext_vector_type(4)));

#define NB 4
#define NT 2048
#define NC 2048
#define NH 16
#define ND 128
#define NROW (NB*NT)   // 8192

#define GLD16(g, l) __builtin_amdgcn_global_load_lds( \
    (__attribute__((address_space(1))) void*)(g), \
    (__attribute__((address_space(3))) void*)(l), 16, 0, 0)

// ---------------- fused: x fp32 -> bf16  AND  omega = sigmoid((x.w_omega+b)/16) ----------------
__global__ void cvtx_omega_kernel(const float* __restrict__ x, bf16* __restrict__ xb,
                                  const float* __restrict__ w_om, const float* __restrict__ b_om,
                                  float* __restrict__ omega) {
  int row = blockIdx.x;
  const float4* xr = reinterpret_cast<const float4*>(x + (size_t)row * NC);
  const float4* wr = reinterpret_cast<const float4*>(w_om);
  bf16x4v* ob = reinterpret_cast<bf16x4v*>(xb + (size_t)row * NC);
  float sum = 0.f;
  for (int i = threadIdx.x; i < NC/4; i += 256) {
    float4 a = xr[i], b = wr[i];
    sum += a.x*b.x + a.y*b.y + a.z*b.z + a.w*b.w;
    bf16x4v o;
    o[0] = (bf16)a.x; o[1] = (bf16)a.y; o[2] = (bf16)a.z; o[3] = (bf16)a.w;
    ob[i] = o;
  }
  for (int m = 32; m; m >>= 1) sum += __shfl_xor(sum, m);
  __shared__ float wsum[4];
  if ((threadIdx.x & 63) == 0) wsum[threadIdx.x >> 6] = sum;
  __syncthreads();
  if (threadIdx.x == 0) {
    float d = wsum[0] + wsum[1] + wsum[2] + wsum[3] + b_om[0];
    omega[row] = 1.f / (1.f + expf(-d * (1.f/16.f)));
  }
}

// ---------------- fp32 -> bf16 convert: all 4 weight matrices in one launch ----------------
__global__ void cvtw_kernel(const float* __restrict__ W0, const float* __restrict__ W1,
                            const float* __restrict__ W2, const float* __restrict__ W3,
                            bf16* __restrict__ o0, bf16* __restrict__ o1,
                            bf16* __restrict__ o2, bf16* __restrict__ o3) {
  int which = blockIdx.x >> 12;   // 4096 blocks per weight
  const float* in = which == 0 ? W0 : which == 1 ? W1 : which == 2 ? W2 : W3;
  bf16* out = which == 0 ? o0 : which == 1 ? o1 : which == 2 ? o2 : o3;
  int i = (blockIdx.x & 4095) * 256 + threadIdx.x;   // < NC*NC/4
  float4 v = reinterpret_cast<const float4*>(in)[i];
  bf16x4v o;
  o[0] = (bf16)v.x; o[1] = (bf16)v.y; o[2] = (bf16)v.z; o[3] = (bf16)v.w;
  reinterpret_cast<bf16x4v*>(out)[i] = o;
}

// ---------------- exclusive cumsum over T per batch (fp64 accumulation) ----------------
__global__ void scan_kernel(const float* __restrict__ omega, float* __restrict__ phi) {
  int b = blockIdx.x;
  const float* om = omega + (size_t)b * NT;
  float* ph = phi + (size_t)b * NT;
  int t = threadIdx.x;
  float v[8]; float s = 0.f;
  #pragma unroll
  for (int j = 0; j < 8; j++) { v[j] = om[t*8 + j]; s += v[j]; }
  __shared__ float totals[256];
  __shared__ double base_sh[256];
  totals[t] = s;
  __syncthreads();
  if (t == 0) {
    double run = 0.0;
    for (int i = 0; i < 256; i++) { base_sh[i] = run; run += (double)totals[i]; }
  }
  __syncthreads();
  double run = base_sh[t];
  #pragma unroll
  for (int j = 0; j < 8; j++) { ph[t*8 + j] = (float)run; run += (double)v[j]; }
}

// ---------------- cos/sin table: [row][dd], dd in 0..63 ----------------
__global__ void sincos_kernel(const float* __restrict__ phi, const float* __restrict__ log_freq,
                              float* __restrict__ cos_t, float* __restrict__ sin_t) {
  int i = blockIdx.x * 256 + threadIdx.x;   // < NROW*64
  int row = i >> 6, dd = i & 63;
  float f = expf(log_freq[dd]);
  float a = phi[row] * f;
  float si, co;
  sincosf(a, &si, &co);
  cos_t[i] = co;
  sin_t[i] = si;
}

// ---------------- 256x256 GEMM (round-6 structure, measured best) ----------------
// 512 threads = 8 waves (4M x 2N), BK=64, LDS 128KB dbuf.
// Stage A(next) in ph1, B(next) in ph2; single vmcnt(0) drain per tile boundary.
// MODE 0: rotate+rmsnorm epilogue (x outscale), bf16 | MODE 1: bf16 transposed Vt | MODE 2: fp32
template<int MODE>
__global__ __launch_bounds__(512, 2)
void gemm256(const bf16* __restrict__ Ag, const bf16* __restrict__ Bg,
             void* __restrict__ Cout,
             const float* __restrict__ cos_t, const float* __restrict__ sin_t,
             const float* __restrict__ gamma, float outscale) {
  constexpr int NKT = NC / 64;   // 32 K-tiles
  __shared__ bf16 Als[2][256 * 64];
  __shared__ bf16 Bls[2][256 * 64];
  const int t = threadIdx.x;
  const int lane = t & 63, lg = lane >> 4, l15 = lane & 15;
  const int wid = t >> 6, wm = wid >> 1, wn = wid & 1;
  const int bid = blockIdx.x;
  const int wg = (bid & 7) * 32 + (bid >> 3);
  const int m0 = (wg >> 3) * 256, n0 = (wg & 7) * 256;

  const size_t K2 = (size_t)NC * 2;
  const int scol = ((t & 7) * 16) ^ (((t >> 3) & 7) << 4);
  const char* aS = (const char*)Ag + (size_t)(m0 + (t >> 3)) * K2 + scol;
  const char* bS = (const char*)Bg + (size_t)(n0 + (t >> 3)) * K2 + scol;

  const int colk0 = (lg * 16) ^ ((l15 & 7) << 4);
  const int colk[2] = { colk0, colk0 ^ 64 };
  const int arow = (wm * 64 + l15) * 128;
  const int brow = (wn * 128 + l15) * 128;

  f32x4 acc[4][8] = {};

#define STAGE_TA(kt, d) do { \
    const char* sa_ = aS + (size_t)(kt) * 128; \
    char* da_ = (char*)&Als[d][0] + t * 16; \
    GLD16(sa_,            da_); \
    GLD16(sa_ +  64*K2,   da_ + 8192); \
    GLD16(sa_ + 128*K2,   da_ + 16384); \
    GLD16(sa_ + 192*K2,   da_ + 24576); \
  } while(0)
#define STAGE_TB(kt, d) do { \
    const char* sb_ = bS + (size_t)(kt) * 128; \
    char* db_ = (char*)&Bls[d][0] + t * 16; \
    GLD16(sb_,            db_); \
    GLD16(sb_ +  64*K2,   db_ + 8192); \
    GLD16(sb_ + 128*K2,   db_ + 16384); \
    GLD16(sb_ + 192*K2,   db_ + 24576); \
  } while(0)

  STAGE_TA(0, 0); STAGE_TB(0, 0);
  asm volatile("s_waitcnt vmcnt(0)" ::: "memory");
  __builtin_amdgcn_s_barrier();
  asm volatile("" ::: "memory");

  bf16x8 aC[2][2], bC[4][2];
  for (int kt = 0; kt < NKT; kt++) {
    const int d = kt & 1;
    const char* Ab = (const char*)&Als[d][0];
    const char* Bb = (const char*)&Bls[d][0];
    const bool pf = (kt + 1 < NKT);

    // ---- ph1: read A(M0)+B(N0); stage A(next); MFMA M0N0 ----
    #pragma unroll
    for (int i = 0; i < 2; i++)
      #pragma unroll
      for (int kk = 0; kk < 2; kk++)
        aC[i][kk] = *(const bf16x8*)(Ab + arow + (i*16)*128 + colk[kk]);
    #pragma unroll
    for (int j = 0; j < 4; j++)
      #pragma unroll
      for (int kk = 0; kk < 2; kk++)
        bC[j][kk] = *(const bf16x8*)(Bb + brow + (j*16)*128 + colk[kk]);
    if (pf) STAGE_TA(kt+1, d^1);
    __builtin_amdgcn_s_barrier();
    asm volatile("s_waitcnt lgkmcnt(0)");
    __builtin_amdgcn_s_setprio(1);
    #pragma unroll
    for (int kk = 0; kk < 2; kk++)
      #pragma unroll
      for (int i = 0; i < 2; i++)
        #pragma unroll
        for (int j = 0; j < 4; j++)
          acc[i][j] = __builtin_amdgcn_mfma_f32_16x16x32_bf16(aC[i][kk], bC[j][kk], acc[i][j], 0,0,0);
    __builtin_amdgcn_s_setprio(0);

    // ---- ph2: read A(M1); stage B(next); MFMA M1N0 ----
    #pragma unroll
    for (int i = 0; i < 2; i++)
      #pragma unroll
      for (int kk = 0; kk < 2; kk++)
        aC[i][kk] = *(const bf16x8*)(Ab + arow + ((32 + i*16))*128 + colk[kk]);
    if (pf) STAGE_TB(kt+1, d^1);
    __builtin_amdgcn_s_barrier();
    asm volatile("s_waitcnt lgkmcnt(0)");
    __builtin_amdgcn_s_setprio(1);
    #pragma unroll
    for (int kk = 0; kk < 2; kk++)
      #pragma unroll
      for (int i = 0; i < 2; i++)
        #pragma unroll
        for (int j = 0; j < 4; j++)
          acc[2+i][j] = __builtin_amdgcn_mfma_f32_16x16x32_bf16(aC[i][kk], bC[j][kk], acc[2+i][j], 0,0,0);
    __builtin_amdgcn_s_setprio(0);

    // ---- ph3: read B(N1); MFMA M1N1 ----
    #pragma unroll
    for (int j = 0; j < 4; j++)
      #pragma unroll
      for (int kk = 0; kk < 2; kk++)
        bC[j][kk] = *(const bf16x8*)(Bb + brow + ((64 + j*16))*128 + colk[kk]);
    __builtin_amdgcn_s_barrier();
    asm volatile("s_waitcnt lgkmcnt(0)");
    __builtin_amdgcn_s_setprio(1);
    #pragma unroll
    for (int kk = 0; kk < 2; kk++)
      #pragma unroll
      for (int i = 0; i < 2; i++)
        #pragma unroll
        for (int j = 0; j < 4; j++)
          acc[2+i][4+j] = __builtin_amdgcn_mfma_f32_16x16x32_bf16(aC[i][kk], bC[j][kk], acc[2+i][4+j], 0,0,0);
    __builtin_amdgcn_s_setprio(0);

    // ---- ph4: re-read A(M0); MFMA M0N1 ----
    #pragma unroll
    for (int i = 0; i < 2; i++)
      #pragma unroll
      for (int kk = 0; kk < 2; kk++)
        aC[i][kk] = *(const bf16x8*)(Ab + arow + (i*16)*128 + colk[kk]);
    __builtin_amdgcn_s_barrier();
    asm volatile("s_waitcnt lgkmcnt(0)");
    __builtin_amdgcn_s_setprio(1);
    #pragma unroll
    for (int kk = 0; kk < 2; kk++)
      #pragma unroll
      for (int i = 0; i < 2; i++)
        #pragma unroll
        for (int j = 0; j < 4; j++)
          acc[i][4+j] = __builtin_amdgcn_mfma_f32_16x16x32_bf16(aC[i][kk], bC[j][kk], acc[i][4+j], 0,0,0);
    __builtin_amdgcn_s_setprio(0);

    asm volatile("s_waitcnt vmcnt(0)" ::: "memory");
    __builtin_amdgcn_s_barrier();
    asm volatile("" ::: "memory");
  }
#undef STAGE_TA
#undef STAGE_TB

  if constexpr (MODE == 0) {
    bf16* out = (bf16*)Cout;
    #pragma unroll
    for (int mi = 0; mi < 4; mi++) {
      #pragma unroll
      for (int r = 0; r < 4; r++) {
        int m = m0 + wm*64 + mi*16 + lg*4 + r;
        float ss = 0.f;
        #pragma unroll
        for (int nj = 0; nj < 8; nj++) { float v = acc[mi][nj][r]; ss += v*v; }
        ss += __shfl_xor(ss, 1); ss += __shfl_xor(ss, 2);
        ss += __shfl_xor(ss, 4); ss += __shfl_xor(ss, 8);
        float scale = rsqrtf(ss * (1.f/128.f) + 1e-5f) * outscale;
        size_t rowb = (size_t)m * NC + n0 + wn*128;
        size_t tabb = (size_t)m * 64;
        #pragma unroll
        for (int nj = 0; nj < 4; nj++) {
          int dd = nj*16 + l15;
          float c = cos_t[tabb + dd];
          float s = sin_t[tabb + dd];
          float t1 = acc[mi][nj][r], t2 = acc[mi][nj+4][r];
          float o1 = (t1*c + t2*s) * scale * gamma[dd];
          float o2 = (t2*c - t1*s) * scale * gamma[dd + 64];
          out[rowb + dd] = (bf16)o1;
          out[rowb + dd + 64] = (bf16)o2;
        }
      }
    }
  } else if constexpr (MODE == 1) {
    bf16* vt = (bf16*)Cout;
    const int h = (n0 + wn*128) >> 7;
    #pragma unroll
    for (int mi = 0; mi < 4; mi++) {
      #pragma unroll
      for (int r = 0; r < 4; r++) {
        int m = m0 + wm*64 + mi*16 + lg*4 + r;
        int bidx = m >> 11, tt = m & (NT-1);
        size_t hb = (((size_t)bidx * NH + h) * ND) * NT + tt;
        #pragma unroll
        for (int nj = 0; nj < 8; nj++) {
          int d = nj*16 + l15;
          vt[hb + (size_t)d * NT] = (bf16)acc[mi][nj][r];
        }
      }
    }
  } else {
    float* out = (float*)Cout;
    #pragma unroll
    for (int mi = 0; mi < 4; mi++) {
      #pragma unroll
      for (int r = 0; r < 4; r++) {
        int m = m0 + wm*64 + mi*16 + lg*4 + r;
        size_t rowb = (size_t)m * NC + n0 + wn*128;
        #pragma unroll
        for (int nj = 0; nj < 8; nj++)
          out[rowb + nj*16 + l15] = acc[mi][nj][r];
      }
    }
  }
}

// ---------------- causal flash attention v5: single barrier per tile ----------------
// grid: (B*H, T/256), block 512 (8 waves x 32 q-rows), KV tile = 64.
// K AND V double-buffered (32+32 KB), P per-wave swizzled (32 KB) -> 96 KB, 1 block/CU.
// All of tile t+1's staging issued at top of tile t; ONE vmcnt(0)+barrier at tile end
// (P write->read is wave-local: lgkmcnt only, no barrier). Waves decouple within a tile.
__global__ __launch_bounds__(512, 2)
void fa_kernel(const bf16* __restrict__ Qg, const bf16* __restrict__ Kg,
               const bf16* __restrict__ Vt, bf16* __restrict__ Og) {
  __shared__ bf16 Kls[2][64 * 128];   // 32 KB
  __shared__ bf16 Vls[2][128 * 64];   // 32 KB
  __shared__ bf16 Pls[8][32 * 64];    // 32 KB, XOR-swizzled rows (per-wave)
  const int t = threadIdx.x, w = t >> 6, lane = t & 63, lg = lane >> 4, l15 = lane & 15;
  const int bh = blockIdx.x;
  const int qb = (gridDim.y - 1) - blockIdx.y;   // big blocks dispatch first
  const size_t qkbase = (size_t)(bh >> 4) * NT * NC + (size_t)(bh & 15) * ND;
  const size_t vbase  = (size_t)bh * ND * NT;
  const int q0 = qb * 256 + w * 32;

  bf16x8 qf[2][4];
  #pragma unroll
  for (int mt = 0; mt < 2; mt++)
    #pragma unroll
    for (int kc = 0; kc < 4; kc++)
      qf[mt][kc] = *reinterpret_cast<const bf16x8*>(
          Qg + qkbase + (size_t)(q0 + mt*16 + l15) * NC + kc*32 + lg*8);

  f32x4 oacc[2][8] = {};
  f32x4 lacc[2] = {};
  float m_run[2][4];
  #pragma unroll
  for (int mt = 0; mt < 2; mt++)
    #pragma unroll
    for (int r = 0; r < 4; r++) m_run[mt][r] = -1e30f;

  bf16x8 vone;
  #pragma unroll
  for (int i = 0; i < 8; i++) vone[i] = (bf16)1.0f;

  // staging maps (XOR-swizzled source, linear LDS dest)
  const int kinS = ((t & 15) * 16) ^ (((t >> 4) & 7) << 4);
  const char* ksrc0 = (const char*)(Kg + qkbase) + (size_t)(t >> 4) * (NC*2) + kinS;
  const int vinS = ((t & 7) * 16) ^ (((t >> 3) & 7) << 4);
  const char* vsrc0 = (const char*)(Vt + vbase) + (size_t)(t >> 3) * (NT*2) + vinS;

#define STAGE_KV(kt, dd) do { \
    const char* ks_ = ksrc0 + (size_t)(kt) * 64 * (NC*2); \
    const char* vs_ = vsrc0 + (size_t)(kt) * 128; \
    char* kd_ = (char*)&Kls[dd][0] + t * 16; \
    char* vd_ = (char*)&Vls[dd][0] + t * 16; \
    GLD16(ks_,                        kd_); \
    GLD16(ks_ + (size_t)32 * NC * 2,  kd_ + 8192); \
    GLD16(vs_,                        vd_); \
    GLD16(vs_ + (size_t)64 * NT * 2,  vd_ + 8192); \
  } while(0)

  const int ntiles = 4 * qb + 4;
  STAGE_KV(0, 0);
  asm volatile("s_waitcnt vmcnt(0)" ::: "memory");
  __builtin_amdgcn_s_barrier();
  asm volatile("" ::: "memory");

  for (int kt = 0; kt < ntiles; kt++) {
    const int d = kt & 1;
    const int kv0 = kt * 64;
    if (kt + 1 < ntiles) STAGE_KV(kt + 1, d ^ 1);

    if (q0 + 31 >= kv0) {
      // ---- S = Q K^T (q pre-scaled by log2e/sqrt(D)) ----
      f32x4 s[2][4] = {};
      __builtin_amdgcn_s_setprio(1);
      #pragma unroll
      for (int kc = 0; kc < 4; kc++) {
        bf16x8 kf[4];
        const int swz = ((kc*64 + lg*16) ^ ((l15 & 7) << 4));
        #pragma unroll
        for (int nt = 0; nt < 4; nt++)
          kf[nt] = *reinterpret_cast<const bf16x8*>((const char*)&Kls[d][0] + (nt*16 + l15) * 256 + swz);
        #pragma unroll
        for (int mt = 0; mt < 2; mt++)
          #pragma unroll
          for (int nt = 0; nt < 4; nt++)
            s[mt][nt] = __builtin_amdgcn_mfma_f32_16x16x32_bf16(qf[mt][kc], kf[nt], s[mt][nt], 0, 0, 0);
      }
      __builtin_amdgcn_s_setprio(0);

      // ---- mask (diagonal region only) ----
      if (kv0 + 63 > q0) {
        #pragma unroll
        for (int mt = 0; mt < 2; mt++)
          #pragma unroll
          for (int nt = 0; nt < 4; nt++) {
            int kv = kv0 + nt*16 + l15;
            #pragma unroll
            for (int r = 0; r < 4; r++)
              if (kv > q0 + mt*16 + lg*4 + r) s[mt][nt][r] = -1e30f;
          }
      }

      // ---- row maxima ----
      float tmax[2][4];
      #pragma unroll
      for (int mt = 0; mt < 2; mt++)
        #pragma unroll
        for (int r = 0; r < 4; r++) {
          float tm = fmaxf(fmaxf(s[mt][0][r], s[mt][1][r]), fmaxf(s[mt][2][r], s[mt][3][r]));
          tm = fmaxf(tm, __shfl_xor(tm, 1));
          tm = fmaxf(tm, __shfl_xor(tm, 2));
          tm = fmaxf(tm, __shfl_xor(tm, 4));
          tm = fmaxf(tm, __shfl_xor(tm, 8));
          tmax[mt][r] = tm;
        }

      // ---- defer-rescale, THR=8 (log2 domain) ----
      int ok = 1;
      #pragma unroll
      for (int mt = 0; mt < 2; mt++)
        #pragma unroll
        for (int r = 0; r < 4; r++) ok &= (tmax[mt][r] <= m_run[mt][r] + 8.0f);
      if (!__all(ok)) {
        #pragma unroll
        for (int mt = 0; mt < 2; mt++) {
          f32x4 alv;
          #pragma unroll
          for (int r = 0; r < 4; r++) {
            float mn = fmaxf(m_run[mt][r], tmax[mt][r]);
            alv[r] = exp2f(m_run[mt][r] - mn);
            m_run[mt][r] = mn;
          }
          #pragma unroll
          for (int dt = 0; dt < 8; dt++) {
            f32x4 o = oacc[mt][dt];
            o[0] *= alv[0]; o[1] *= alv[1]; o[2] *= alv[2]; o[3] *= alv[3];
            oacc[mt][dt] = o;
          }
          f32x4 lv = lacc[mt];
          lv[0] *= alv[0]; lv[1] *= alv[1]; lv[2] *= alv[2]; lv[3] *= alv[3];
          lacc[mt] = lv;
        }
      }

      // ---- P = exp2(s - m) -> swizzled per-wave LDS ----
      char* pw = (char*)&Pls[w][0];
      #pragma unroll
      for (int mt = 0; mt < 2; mt++)
        #pragma unroll
        for (int r = 0; r < 4; r++) {
          float p0 = exp2f(s[mt][0][r] - m_run[mt][r]);
          float p1 = exp2f(s[mt][1][r] - m_run[mt][r]);
          float p2 = exp2f(s[mt][2][r] - m_run[mt][r]);
          float p3 = exp2f(s[mt][3][r] - m_run[mt][r]);
          int qrow = mt*16 + lg*4 + r;
          int rb = qrow * 128, cX = (qrow & 7) << 4;
          *(bf16*)(pw + rb + ((       2*l15) ^ cX)) = (bf16)p0;
          *(bf16*)(pw + rb + (( 32 +  2*l15) ^ cX)) = (bf16)p1;
          *(bf16*)(pw + rb + (( 64 +  2*l15) ^ cX)) = (bf16)p2;
          *(bf16*)(pw + rb + (( 96 +  2*l15) ^ cX)) = (bf16)p3;
        }

      // P write -> read is wave-local: wait LDS ops only (no barrier)
      asm volatile("s_waitcnt lgkmcnt(0)" ::: "memory");

      // ---- O += P V ; l += P 1 ----
      bf16x8 pf[2][2];
      #pragma unroll
      for (int mt = 0; mt < 2; mt++)
        #pragma unroll
        for (int kc2 = 0; kc2 < 2; kc2++)
          pf[mt][kc2] = *reinterpret_cast<const bf16x8*>(
              pw + (mt*16 + l15) * 128 + ((kc2*64 + lg*16) ^ ((l15 & 7) << 4)));
      __builtin_amdgcn_s_setprio(1);
      #pragma unroll
      for (int kc2 = 0; kc2 < 2; kc2++) {
        #pragma unroll
        for (int mt = 0; mt < 2; mt++)
          lacc[mt] = __builtin_amdgcn_mfma_f32_16x16x32_bf16(pf[mt][kc2], vone, lacc[mt], 0, 0, 0);
        const int swz = ((kc2*64 + lg*16) ^ ((l15 & 7) << 4));
        #pragma unroll
        for (int dt = 0; dt < 8; dt++) {
          bf16x8 vf = *reinterpret_cast<const bf16x8*>((const char*)&Vls[d][0] + (dt*16 + l15) * 128 + swz);
          #pragma unroll
          for (int mt = 0; mt < 2; mt++)
            oacc[mt][dt] = __builtin_amdgcn_mfma_f32_16x16x32_bf16(pf[mt][kc2], vf, oacc[mt][dt], 0, 0, 0);
        }
      }
      __builtin_amdgcn_s_setprio(0);
    }

    // ---- single per-tile sync: staging for t+1 landed; WAR-safe to overwrite next iter ----
    asm volatile("s_waitcnt vmcnt(0)" ::: "memory");
    __builtin_amdgcn_s_barrier();
    asm volatile("" ::: "memory");
  }
#undef STAGE_KV

  // ---- epilogue ----
  #pragma unroll
  for (int mt = 0; mt < 2; mt++)
    #pragma unroll
    for (int r = 0; r < 4; r++) {
      float inv = 1.f / lacc[mt][r];
      size_t orow = qkbase + (size_t)(q0 + mt*16 + lg*4 + r) * NC;
      #pragma unroll
      for (int dt = 0; dt < 8; dt++)
        Og[orow + dt*16 + l15] = (bf16)(oacc[mt][dt][r] * inv);
    }
}

// ---------------- host launch ----------------
extern "C" void kernel_launch(void* const* d_in, const int* in_sizes, int n_in,
                              void* d_out, int out_size, void* d_ws, size_t ws_size,
                              hipStream_t stream) {
  (void)in_sizes; (void)n_in; (void)out_size; (void)ws_size;
  const float* x       = (const float*)d_in[0];
  const float* Wq      = (const float*)d_in[1];
  const float* Wk      = (const float*)d_in[2];
  const float* Wv      = (const float*)d_in[3];
  const float* Wo      = (const float*)d_in[4];
  const float* w_omega = (const float*)d_in[5];
  const float* b_omega = (const float*)d_in[6];
  const float* log_freq= (const float*)d_in[7];
  const float* q_gamma = (const float*)d_in[8];
  const float* k_gamma = (const float*)d_in[9];

  char* p = (char*)d_ws;
  auto alloc = [&](size_t bytes) { void* r = (void*)p; p += (bytes + 255) & ~(size_t)255; return r; };
  bf16* xb   = (bf16*)alloc((size_t)NROW * NC * 2);
  bf16* wqb  = (bf16*)alloc((size_t)NC * NC * 2);
  bf16* wkb  = (bf16*)alloc((size_t)NC * NC * 2);
  bf16* wvb  = (bf16*)alloc((size_t)NC * NC * 2);
  bf16* wob  = (bf16*)alloc((size_t)NC * NC * 2);
  bf16* qb   = (bf16*)alloc((size_t)NROW * NC * 2);
  bf16* kb   = (bf16*)alloc((size_t)NROW * NC * 2);
  bf16* vt   = (bf16*)alloc((size_t)NROW * NC * 2);  // transposed V: [B][H][D][T]
  bf16* ob   = (bf16*)alloc((size_t)NROW * NC * 2);
  float* omega = (float*)alloc((size_t)NROW * 4);
  float* phi   = (float*)alloc((size_t)NROW * 4);
  float* cos_t = (float*)alloc((size_t)NROW * 64 * 4);
  float* sin_t = (float*)alloc((size_t)NROW * 64 * 4);

  cvtx_omega_kernel<<<NROW, 256, 0, stream>>>(x, xb, w_omega, b_omega, omega);
  cvtw_kernel<<<16384, 256, 0, stream>>>(Wq, Wk, Wv, Wo, wqb, wkb, wvb, wob);
  scan_kernel<<<NB, 256, 0, stream>>>(omega, phi);
  sincos_kernel<<<NROW * 64 / 256, 256, 0, stream>>>(phi, log_freq, cos_t, sin_t);

  const float sc2 = 0.12751726f;   // log2(e)/sqrt(128), folded into q
  gemm256<0><<<256, 512, 0, stream>>>(xb, wqb, qb, cos_t, sin_t, q_gamma, sc2);
  gemm256<0><<<256, 512, 0, stream>>>(xb, wkb, kb, cos_t, sin_t, k_gamma, 1.0f);
  gemm256<1><<<256, 512, 0, stream>>>(xb, wvb, vt, nullptr, nullptr, nullptr, 1.0f);

  fa_kernel<<<dim3(NB * NH, NT / 256), 512, 0, stream>>>(qb, kb, vt, ob);

  gemm256<2><<<256, 512, 0, stream>>>(ob, wob, d_out, nullptr, nullptr, nullptr, 1.0f);
}

// Round 9
// 423.366 us; speedup vs baseline: 1.2089x; 1.0931x over previous
//
#include <hip/hip_runtime.h>
#include <math.h>

typedef __bf16 bf16;
typedef __bf16 bf16x8 __attribute__((ext_vector_type(8)));
typedef __bf16 bf16x4v __attribute__((ext_vector_type(4)));
typedef float f32x4 __attribute__((ext_vector_type(4)));

#define NB 4
#define NT 2048
#define NC 2048
#define NH 16
#define ND 128
#define NROW (NB*NT)   // 8192

#define GLD16(g, l) __builtin_amdgcn_global_load_lds( \
    (__attribute__((address_space(1))) void*)(g), \
    (__attribute__((address_space(3))) void*)(l), 16, 0, 0)

// ---------------- fused: x fp32 -> bf16  AND  omega = sigmoid((x.w_omega+b)/16) ----------------
__global__ void cvtx_omega_kernel(const float* __restrict__ x, bf16* __restrict__ xb,
                                  const float* __restrict__ w_om, const float* __restrict__ b_om,
                                  float* __restrict__ omega) {
  int row = blockIdx.x;
  const float4* xr = reinterpret_cast<const float4*>(x + (size_t)row * NC);
  const float4* wr = reinterpret_cast<const float4*>(w_om);
  bf16x4v* ob = reinterpret_cast<bf16x4v*>(xb + (size_t)row * NC);
  float sum = 0.f;
  for (int i = threadIdx.x; i < NC/4; i += 256) {
    float4 a = xr[i], b = wr[i];
    sum += a.x*b.x + a.y*b.y + a.z*b.z + a.w*b.w;
    bf16x4v o;
    o[0] = (bf16)a.x; o[1] = (bf16)a.y; o[2] = (bf16)a.z; o[3] = (bf16)a.w;
    ob[i] = o;
  }
  for (int m = 32; m; m >>= 1) sum += __shfl_xor(sum, m);
  __shared__ float wsum[4];
  if ((threadIdx.x & 63) == 0) wsum[threadIdx.x >> 6] = sum;
  __syncthreads();
  if (threadIdx.x == 0) {
    float d = wsum[0] + wsum[1] + wsum[2] + wsum[3] + b_om[0];
    omega[row] = 1.f / (1.f + expf(-d * (1.f/16.f)));
  }
}

// ---------------- fp32 -> bf16 convert: all 4 weight matrices in one launch ----------------
__global__ void cvtw_kernel(const float* __restrict__ W0, const float* __restrict__ W1,
                            const float* __restrict__ W2, const float* __restrict__ W3,
                            bf16* __restrict__ o0, bf16* __restrict__ o1,
                            bf16* __restrict__ o2, bf16* __restrict__ o3) {
  int which = blockIdx.x >> 12;
  const float* in = which == 0 ? W0 : which == 1 ? W1 : which == 2 ? W2 : W3;
  bf16* out = which == 0 ? o0 : which == 1 ? o1 : which == 2 ? o2 : o3;
  int i = (blockIdx.x & 4095) * 256 + threadIdx.x;
  float4 v = reinterpret_cast<const float4*>(in)[i];
  bf16x4v o;
  o[0] = (bf16)v.x; o[1] = (bf16)v.y; o[2] = (bf16)v.z; o[3] = (bf16)v.w;
  reinterpret_cast<bf16x4v*>(out)[i] = o;
}

// ---------------- exclusive cumsum over T per batch (fp64 accumulation) ----------------
__global__ void scan_kernel(const float* __restrict__ omega, float* __restrict__ phi) {
  int b = blockIdx.x;
  const float* om = omega + (size_t)b * NT;
  float* ph = phi + (size_t)b * NT;
  int t = threadIdx.x;
  float v[8]; float s = 0.f;
  #pragma unroll
  for (int j = 0; j < 8; j++) { v[j] = om[t*8 + j]; s += v[j]; }
  __shared__ float totals[256];
  __shared__ double base_sh[256];
  totals[t] = s;
  __syncthreads();
  if (t == 0) {
    double run = 0.0;
    for (int i = 0; i < 256; i++) { base_sh[i] = run; run += (double)totals[i]; }
  }
  __syncthreads();
  double run = base_sh[t];
  #pragma unroll
  for (int j = 0; j < 8; j++) { ph[t*8 + j] = (float)run; run += (double)v[j]; }
}

// ---------------- cos/sin table: [row][dd], dd in 0..63 ----------------
__global__ void sincos_kernel(const float* __restrict__ phi, const float* __restrict__ log_freq,
                              float* __restrict__ cos_t, float* __restrict__ sin_t) {
  int i = blockIdx.x * 256 + threadIdx.x;
  int row = i >> 6, dd = i & 63;
  float f = expf(log_freq[dd]);
  float a = phi[row] * f;
  float si, co;
  sincosf(a, &si, &co);
  cos_t[i] = co;
  sin_t[i] = si;
}

// ---------------- 256x256 GEMM, m201-style 8-phase counted-vmcnt pipeline ----------------
// 512 threads = 8 waves (4M x 2N). BK=64, 2 K-tiles per iteration (8 phases), LDS 128KB.
// Staging in 4 units of 16KB (A1=wave-M0 rows, A2=wave-M1, B1=wave-N0, B2=wave-N1),
// one unit staged per phase 3-6 phases before first use; vmcnt(6)/vmcnt(4) counted waits
// placed pre-barrier of the phase before the dependent reads. Loads never drain to 0.
// MODE 0: rotate+rmsnorm epilogue (x outscale), bf16 | MODE 1: bf16 transposed Vt | MODE 2: fp32
template<int MODE>
__global__ __launch_bounds__(512, 2)
void gemm256(const bf16* __restrict__ Ag, const bf16* __restrict__ Bg,
             void* __restrict__ Cout,
             const float* __restrict__ cos_t, const float* __restrict__ sin_t,
             const float* __restrict__ gamma, float outscale) {
  __shared__ bf16 Als[2][256 * 64];
  __shared__ bf16 Bls[2][256 * 64];
  const int t = threadIdx.x;
  const int lane = t & 63, lg = lane >> 4, l15 = lane & 15;
  const int wid = t >> 6, wm = wid >> 1, wn = wid & 1;
  const int bid = blockIdx.x;
  const int wg = (bid & 7) * 32 + (bid >> 3);
  const int m0 = (wg >> 3) * 256, n0 = (wg & 7) * 256;

  const size_t K2 = (size_t)NC * 2;
  const int u = t >> 3;
  const int scol = ((t & 7) * 16) ^ ((u & 7) << 4);
  // unit sources: A1 rows = (u>>5)*64 + (u&31) (+128 for 2nd load); A2 = +32.
  //               B1 rows = u (+128); B2 = +64.
  const char* a1S = (const char*)Ag + (size_t)(m0 + (u >> 5) * 64 + (u & 31)) * K2 + scol;
  const char* b1S = (const char*)Bg + (size_t)(n0 + u) * K2 + scol;

  const int colk0 = (lg * 16) ^ ((l15 & 7) << 4);
  const int colk1 = colk0 ^ 64;

  char* const A0u1 = (char*)&Als[0][0];
  char* const A0u2 = A0u1 + 16384;
  char* const A1u1 = (char*)&Als[1][0];
  char* const A1u2 = A1u1 + 16384;
  char* const B0u1 = (char*)&Bls[0][0];
  char* const B0u2 = B0u1 + 16384;
  char* const B1u1 = (char*)&Bls[1][0];
  char* const B1u2 = B1u1 + 16384;

  f32x4 acc[4][8] = {};
  bf16x8 aC[2][2], bC[4][2];

#define STG(src, dst, kt) do { \
    const char* s_ = (src) + (size_t)(kt) * 128; \
    char* d_ = (dst) + t * 16; \
    GLD16(s_, d_); GLD16(s_ + (size_t)128 * K2, d_ + 8192); } while(0)
#define STG_A1(kt, d) STG(a1S, (d) ? A1u1 : A0u1, kt)
#define STG_A2(kt, d) STG(a1S + (size_t)32 * K2, (d) ? A1u2 : A0u2, kt)
#define STG_B1(kt, d) STG(b1S, (d) ? B1u1 : B0u1, kt)
#define STG_B2(kt, d) STG(b1S + (size_t)64 * K2, (d) ? B1u2 : B0u2, kt)

#define RDA(base) do { _Pragma("unroll") \
    for (int i2 = 0; i2 < 2; i2++) { \
      const char* p_ = (base) + (wm * 32 + i2 * 16 + l15) * 128; \
      aC[i2][0] = *(const bf16x8*)(p_ + colk0); \
      aC[i2][1] = *(const bf16x8*)(p_ + colk1); } } while(0)
#define RDB(base) do { _Pragma("unroll") \
    for (int j2 = 0; j2 < 4; j2++) { \
      const char* p_ = (base) + (wn * 64 + j2 * 16 + l15) * 128; \
      bC[j2][0] = *(const bf16x8*)(p_ + colk0); \
      bC[j2][1] = *(const bf16x8*)(p_ + colk1); } } while(0)

#define MM(IB, JB) do { __builtin_amdgcn_s_setprio(1); \
    _Pragma("unroll") \
    for (int kk = 0; kk < 2; kk++) \
      _Pragma("unroll") \
      for (int i2 = 0; i2 < 2; i2++) \
        _Pragma("unroll") \
        for (int j2 = 0; j2 < 4; j2++) \
          acc[(IB)+i2][(JB)+j2] = __builtin_amdgcn_mfma_f32_16x16x32_bf16(aC[i2][kk], bC[j2][kk], acc[(IB)+i2][(JB)+j2], 0,0,0); \
    __builtin_amdgcn_s_setprio(0); } while(0)

#define VM(n) asm volatile("s_waitcnt vmcnt(" #n ")" ::: "memory")
#define BAR() do { __builtin_amdgcn_s_barrier(); asm volatile("" ::: "memory"); } while(0)
#define LGK() asm volatile("s_waitcnt lgkmcnt(0)" ::: "memory")

  // prologue: tile0 fully + B1,A2 of tile1 (issue order matters for vmcnt counts)
  STG_A1(0, 0); STG_A2(0, 0); STG_B1(0, 0); STG_B2(0, 0); STG_B1(1, 1); STG_A2(1, 1);
  VM(6); BAR();

  #pragma unroll 1
  for (int i = 0; i < 15; i++) {
    const int o1 = 2*i + 1, e2 = 2*i + 2, o3 = 2*i + 3;
    // P1: tile e (buf0) M0N0
    RDA(A0u1); RDB(B0u1);           BAR(); STG_A1(o1, 1); LGK(); MM(0, 0);
    // P2: M1N0 ; vmcnt(6) guards P3's B2(e)
    RDA(A0u2); VM(6);               BAR(); STG_B2(o1, 1); LGK(); MM(2, 0);
    // P3: M1N1
    RDB(B0u2);                      BAR(); STG_B1(e2, 0); LGK(); MM(2, 4);
    // P4: M0N1 ; vmcnt(4) guards P5's A1(o),B1(o)
    RDA(A0u1); VM(4);               BAR(); STG_A2(e2, 0); LGK(); MM(0, 4);
    // P5: tile o (buf1) M0N0
    RDA(A1u1); RDB(B1u1);           BAR(); STG_A1(e2, 0); LGK(); MM(0, 0);
    // P6: M1N0 ; vmcnt(6) guards P7's B2(o)
    RDA(A1u2); VM(6);               BAR(); STG_B2(e2, 0); LGK(); MM(2, 0);
    // P7: M1N1
    RDB(B1u2);                      BAR(); STG_B1(o3, 1); LGK(); MM(2, 4);
    // P8: M0N1 ; vmcnt(4) guards next P1's A1(e2),B1(e2)
    RDA(A1u1); VM(4);               BAR(); STG_A2(o3, 1); LGK(); MM(0, 4);
  }
  // last iteration (tiles 30,31): only tile-31 stages remain; adjusted waits
  {
    RDA(A0u1); RDB(B0u1);           BAR(); STG_A1(31, 1); LGK(); MM(0, 0);
    RDA(A0u2); VM(6);               BAR(); STG_B2(31, 1); LGK(); MM(2, 0);
    RDB(B0u2);                      BAR();                LGK(); MM(2, 4);
    RDA(A0u1); VM(2);               BAR();                LGK(); MM(0, 4);
    RDA(A1u1); RDB(B1u1);           BAR();                LGK(); MM(0, 0);
    RDA(A1u2); VM(0);               BAR();                LGK(); MM(2, 0);
    RDB(B1u2);                      BAR();                LGK(); MM(2, 4);
    RDA(A1u1);                      BAR();                LGK(); MM(0, 4);
  }
#undef STG
#undef STG_A1
#undef STG_A2
#undef STG_B1
#undef STG_B2
#undef RDA
#undef RDB
#undef MM
#undef VM
#undef BAR
#undef LGK

  if constexpr (MODE == 0) {
    bf16* out = (bf16*)Cout;
    #pragma unroll
    for (int mi = 0; mi < 4; mi++) {
      #pragma unroll
      for (int r = 0; r < 4; r++) {
        int m = m0 + wm*64 + mi*16 + lg*4 + r;
        float ss = 0.f;
        #pragma unroll
        for (int nj = 0; nj < 8; nj++) { float v = acc[mi][nj][r]; ss += v*v; }
        ss += __shfl_xor(ss, 1); ss += __shfl_xor(ss, 2);
        ss += __shfl_xor(ss, 4); ss += __shfl_xor(ss, 8);
        float scale = rsqrtf(ss * (1.f/128.f) + 1e-5f) * outscale;
        size_t rowb = (size_t)m * NC + n0 + wn*128;
        size_t tabb = (size_t)m * 64;
        #pragma unroll
        for (int nj = 0; nj < 4; nj++) {
          int dd = nj*16 + l15;
          float c = cos_t[tabb + dd];
          float s = sin_t[tabb + dd];
          float t1 = acc[mi][nj][r], t2 = acc[mi][nj+4][r];
          float o1 = (t1*c + t2*s) * scale * gamma[dd];
          float o2 = (t2*c - t1*s) * scale * gamma[dd + 64];
          out[rowb + dd] = (bf16)o1;
          out[rowb + dd + 64] = (bf16)o2;
        }
      }
    }
  } else if constexpr (MODE == 1) {
    bf16* vt = (bf16*)Cout;
    const int h = (n0 + wn*128) >> 7;
    #pragma unroll
    for (int mi = 0; mi < 4; mi++) {
      #pragma unroll
      for (int r = 0; r < 4; r++) {
        int m = m0 + wm*64 + mi*16 + lg*4 + r;
        int bidx = m >> 11, tt = m & (NT-1);
        size_t hb = (((size_t)bidx * NH + h) * ND) * NT + tt;
        #pragma unroll
        for (int nj = 0; nj < 8; nj++) {
          int d = nj*16 + l15;
          vt[hb + (size_t)d * NT] = (bf16)acc[mi][nj][r];
        }
      }
    }
  } else {
    float* out = (float*)Cout;
    #pragma unroll
    for (int mi = 0; mi < 4; mi++) {
      #pragma unroll
      for (int r = 0; r < 4; r++) {
        int m = m0 + wm*64 + mi*16 + lg*4 + r;
        size_t rowb = (size_t)m * NC + n0 + wn*128;
        #pragma unroll
        for (int nj = 0; nj < 8; nj++)
          out[rowb + nj*16 + l15] = acc[mi][nj][r];
      }
    }
  }
}

// ---------------- causal flash attention v5 (unchanged from round 8) ----------------
__global__ __launch_bounds__(512, 2)
void fa_kernel(const bf16* __restrict__ Qg, const bf16* __restrict__ Kg,
               const bf16* __restrict__ Vt, bf16* __restrict__ Og) {
  __shared__ bf16 Kls[2][64 * 128];
  __shared__ bf16 Vls[2][128 * 64];
  __shared__ bf16 Pls[8][32 * 64];
  const int t = threadIdx.x, w = t >> 6, lane = t & 63, lg = lane >> 4, l15 = lane & 15;
  const int bh = blockIdx.x;
  const int qb = (gridDim.y - 1) - blockIdx.y;
  const size_t qkbase = (size_t)(bh >> 4) * NT * NC + (size_t)(bh & 15) * ND;
  const size_t vbase  = (size_t)bh * ND * NT;
  const int q0 = qb * 256 + w * 32;

  bf16x8 qf[2][4];
  #pragma unroll
  for (int mt = 0; mt < 2; mt++)
    #pragma unroll
    for (int kc = 0; kc < 4; kc++)
      qf[mt][kc] = *reinterpret_cast<const bf16x8*>(
          Qg + qkbase + (size_t)(q0 + mt*16 + l15) * NC + kc*32 + lg*8);

  f32x4 oacc[2][8] = {};
  f32x4 lacc[2] = {};
  float m_run[2][4];
  #pragma unroll
  for (int mt = 0; mt < 2; mt++)
    #pragma unroll
    for (int r = 0; r < 4; r++) m_run[mt][r] = -1e30f;

  bf16x8 vone;
  #pragma unroll
  for (int i = 0; i < 8; i++) vone[i] = (bf16)1.0f;

  const int kinS = ((t & 15) * 16) ^ (((t >> 4) & 7) << 4);
  const char* ksrc0 = (const char*)(Kg + qkbase) + (size_t)(t >> 4) * (NC*2) + kinS;
  const int vinS = ((t & 7) * 16) ^ (((t >> 3) & 7) << 4);
  const char* vsrc0 = (const char*)(Vt + vbase) + (size_t)(t >> 3) * (NT*2) + vinS;

#define STAGE_KV(kt, dd) do { \
    const char* ks_ = ksrc0 + (size_t)(kt) * 64 * (NC*2); \
    const char* vs_ = vsrc0 + (size_t)(kt) * 128; \
    char* kd_ = (char*)&Kls[dd][0] + t * 16; \
    char* vd_ = (char*)&Vls[dd][0] + t * 16; \
    GLD16(ks_,                        kd_); \
    GLD16(ks_ + (size_t)32 * NC * 2,  kd_ + 8192); \
    GLD16(vs_,                        vd_); \
    GLD16(vs_ + (size_t)64 * NT * 2,  vd_ + 8192); \
  } while(0)

  const int ntiles = 4 * qb + 4;
  STAGE_KV(0, 0);
  asm volatile("s_waitcnt vmcnt(0)" ::: "memory");
  __builtin_amdgcn_s_barrier();
  asm volatile("" ::: "memory");

  for (int kt = 0; kt < ntiles; kt++) {
    const int d = kt & 1;
    const int kv0 = kt * 64;
    if (kt + 1 < ntiles) STAGE_KV(kt + 1, d ^ 1);

    if (q0 + 31 >= kv0) {
      f32x4 s[2][4] = {};
      __builtin_amdgcn_s_setprio(1);
      #pragma unroll
      for (int kc = 0; kc < 4; kc++) {
        bf16x8 kf[4];
        const int swz = ((kc*64 + lg*16) ^ ((l15 & 7) << 4));
        #pragma unroll
        for (int nt = 0; nt < 4; nt++)
          kf[nt] = *reinterpret_cast<const bf16x8*>((const char*)&Kls[d][0] + (nt*16 + l15) * 256 + swz);
        #pragma unroll
        for (int mt = 0; mt < 2; mt++)
          #pragma unroll
          for (int nt = 0; nt < 4; nt++)
            s[mt][nt] = __builtin_amdgcn_mfma_f32_16x16x32_bf16(qf[mt][kc], kf[nt], s[mt][nt], 0, 0, 0);
      }
      __builtin_amdgcn_s_setprio(0);

      if (kv0 + 63 > q0) {
        #pragma unroll
        for (int mt = 0; mt < 2; mt++)
          #pragma unroll
          for (int nt = 0; nt < 4; nt++) {
            int kv = kv0 + nt*16 + l15;
            #pragma unroll
            for (int r = 0; r < 4; r++)
              if (kv > q0 + mt*16 + lg*4 + r) s[mt][nt][r] = -1e30f;
          }
      }

      float tmax[2][4];
      #pragma unroll
      for (int mt = 0; mt < 2; mt++)
        #pragma unroll
        for (int r = 0; r < 4; r++) {
          float tm = fmaxf(fmaxf(s[mt][0][r], s[mt][1][r]), fmaxf(s[mt][2][r], s[mt][3][r]));
          tm = fmaxf(tm, __shfl_xor(tm, 1));
          tm = fmaxf(tm, __shfl_xor(tm, 2));
          tm = fmaxf(tm, __shfl_xor(tm, 4));
          tm = fmaxf(tm, __shfl_xor(tm, 8));
          tmax[mt][r] = tm;
        }

      int ok = 1;
      #pragma unroll
      for (int mt = 0; mt < 2; mt++)
        #pragma unroll
        for (int r = 0; r < 4; r++) ok &= (tmax[mt][r] <= m_run[mt][r] + 8.0f);
      if (!__all(ok)) {
        #pragma unroll
        for (int mt = 0; mt < 2; mt++) {
          f32x4 alv;
          #pragma unroll
          for (int r = 0; r < 4; r++) {
            float mn = fmaxf(m_run[mt][r], tmax[mt][r]);
            alv[r] = exp2f(m_run[mt][r] - mn);
            m_run[mt][r] = mn;
          }
          #pragma unroll
          for (int dt = 0; dt < 8; dt++) {
            f32x4 o = oacc[mt][dt];
            o[0] *= alv[0]; o[1] *= alv[1]; o[2] *= alv[2]; o[3] *= alv[3];
            oacc[mt][dt] = o;
          }
          f32x4 lv = lacc[mt];
          lv[0] *= alv[0]; lv[1] *= alv[1]; lv[2] *= alv[2]; lv[3] *= alv[3];
          lacc[mt] = lv;
        }
      }

      char* pw = (char*)&Pls[w][0];
      #pragma unroll
      for (int mt = 0; mt < 2; mt++)
        #pragma unroll
        for (int r = 0; r < 4; r++) {
          float p0 = exp2f(s[mt][0][r] - m_run[mt][r]);
          float p1 = exp2f(s[mt][1][r] - m_run[mt][r]);
          float p2 = exp2f(s[mt][2][r] - m_run[mt][r]);
          float p3 = exp2f(s[mt][3][r] - m_run[mt][r]);
          int qrow = mt*16 + lg*4 + r;
          int rb = qrow * 128, cX = (qrow & 7) << 4;
          *(bf16*)(pw + rb + ((       2*l15) ^ cX)) = (bf16)p0;
          *(bf16*)(pw + rb + (( 32 +  2*l15) ^ cX)) = (bf16)p1;
          *(bf16*)(pw + rb + (( 64 +  2*l15) ^ cX)) = (bf16)p2;
          *(bf16*)(pw + rb + (( 96 +  2*l15) ^ cX)) = (bf16)p3;
        }

      asm volatile("s_waitcnt lgkmcnt(0)" ::: "memory");

      bf16x8 pf[2][2];
      #pragma unroll
      for (int mt = 0; mt < 2; mt++)
        #pragma unroll
        for (int kc2 = 0; kc2 < 2; kc2++)
          pf[mt][kc2] = *reinterpret_cast<const bf16x8*>(
              pw + (mt*16 + l15) * 128 + ((kc2*64 + lg*16) ^ ((l15 & 7) << 4)));
      __builtin_amdgcn_s_setprio(1);
      #pragma unroll
      for (int kc2 = 0; kc2 < 2; kc2++) {
        #pragma unroll
        for (int mt = 0; mt < 2; mt++)
          lacc[mt] = __builtin_amdgcn_mfma_f32_16x16x32_bf16(pf[mt][kc2], vone, lacc[mt], 0, 0, 0);
        const int swz = ((kc2*64 + lg*16) ^ ((l15 & 7) << 4));
        #pragma unroll
        for (int dt = 0; dt < 8; dt++) {
          bf16x8 vf = *reinterpret_cast<const bf16x8*>((const char*)&Vls[d][0] + (dt*16 + l15) * 128 + swz);
          #pragma unroll
          for (int mt = 0; mt < 2; mt++)
            oacc[mt][dt] = __builtin_amdgcn_mfma_f32_16x16x32_bf16(pf[mt][kc2], vf, oacc[mt][dt], 0, 0, 0);
        }
      }
      __builtin_amdgcn_s_setprio(0);
    }

    asm volatile("s_waitcnt vmcnt(0)" ::: "memory");
    __builtin_amdgcn_s_barrier();
    asm volatile("" ::: "memory");
  }
#undef STAGE_KV

  #pragma unroll
  for (int mt = 0; mt < 2; mt++)
    #pragma unroll
    for (int r = 0; r < 4; r++) {
      float inv = 1.f / lacc[mt][r];
      size_t orow = qkbase + (size_t)(q0 + mt*16 + lg*4 + r) * NC;
      #pragma unroll
      for (int dt = 0; dt < 8; dt++)
        Og[orow + dt*16 + l15] = (bf16)(oacc[mt][dt][r] * inv);
    }
}

// ---------------- host launch ----------------
extern "C" void kernel_launch(void* const* d_in, const int* in_sizes, int n_in,
                              void* d_out, int out_size, void* d_ws, size_t ws_size,
                              hipStream_t stream) {
  (void)in_sizes; (void)n_in; (void)out_size; (void)ws_size;
  const float* x       = (const float*)d_in[0];
  const float* Wq      = (const float*)d_in[1];
  const float* Wk      = (const float*)d_in[2];
  const float* Wv      = (const float*)d_in[3];
  const float* Wo      = (const float*)d_in[4];
  const float* w_omega = (const float*)d_in[5];
  const float* b_omega = (const float*)d_in[6];
  const float* log_freq= (const float*)d_in[7];
  const float* q_gamma = (const float*)d_in[8];
  const float* k_gamma = (const float*)d_in[9];

  char* p = (char*)d_ws;
  auto alloc = [&](size_t bytes) { void* r = (void*)p; p += (bytes + 255) & ~(size_t)255; return r; };
  bf16* xb   = (bf16*)alloc((size_t)NROW * NC * 2);
  bf16* wqb  = (bf16*)alloc((size_t)NC * NC * 2);
  bf16* wkb  = (bf16*)alloc((size_t)NC * NC * 2);
  bf16* wvb  = (bf16*)alloc((size_t)NC * NC * 2);
  bf16* wob  = (bf16*)alloc((size_t)NC * NC * 2);
  bf16* qb   = (bf16*)alloc((size_t)NROW * NC * 2);
  bf16* kb   = (bf16*)alloc((size_t)NROW * NC * 2);
  bf16* vt   = (bf16*)alloc((size_t)NROW * NC * 2);
  bf16* ob   = (bf16*)alloc((size_t)NROW * NC * 2);
  float* omega = (float*)alloc((size_t)NROW * 4);
  float* phi   = (float*)alloc((size_t)NROW * 4);
  float* cos_t = (float*)alloc((size_t)NROW * 64 * 4);
  float* sin_t = (float*)alloc((size_t)NROW * 64 * 4);

  cvtx_omega_kernel<<<NROW, 256, 0, stream>>>(x, xb, w_omega, b_omega, omega);
  cvtw_kernel<<<16384, 256, 0, stream>>>(Wq, Wk, Wv, Wo, wqb, wkb, wvb, wob);
  scan_kernel<<<NB, 256, 0, stream>>>(omega, phi);
  sincos_kernel<<<NROW * 64 / 256, 256, 0, stream>>>(phi, log_freq, cos_t, sin_t);

  const float sc2 = 0.12751726f;   // log2(e)/sqrt(128), folded into q
  gemm256<0><<<256, 512, 0, stream>>>(xb, wqb, qb, cos_t, sin_t, q_gamma, sc2);
  gemm256<0><<<256, 512, 0, stream>>>(xb, wkb, kb, cos_t, sin_t, k_gamma, 1.0f);
  gemm256<1><<<256, 512, 0, stream>>>(xb, wvb, vt, nullptr, nullptr, nullptr, 1.0f);

  fa_kernel<<<dim3(NB * NH, NT / 256), 512, 0, stream>>>(qb, kb, vt, ob);

  gemm256<2><<<256, 512, 0, stream>>>(ob, wob, d_out, nullptr, nullptr, nullptr, 1.0f);
}